// Round 5
// baseline (19356.102 us; speedup 1.0000x reference)
//
#include <hip/hip_runtime.h>
#include <cstdint>
#include <cstddef>

typedef unsigned short u16;
typedef unsigned int u32;
typedef unsigned long long u64;
typedef short bf16x8 __attribute__((ext_vector_type(8)));
typedef float f32x4 __attribute__((ext_vector_type(4)));
typedef unsigned short u16x4 __attribute__((ext_vector_type(4)));

#define T_LEN 1200

// workspace byte offsets (all 256-aligned). Total ~48.0 MB.
#define O_X     0ull           // x bf16: 38400*512*2        = 39,321,600
#define O_WIH   39321600ull    // W_ih cat bf16: 4096*512*2  =  4,194,304
#define O_WHH   43515904ull    // W_hh cat bf16: 4096*512*2  =  4,194,304
#define O_BIAS  47710208ull    // bias cat f32: 4096*4       =     16,384
#define O_HBUF  47726592ull    // tagged h dwords: 2 par * 2 dir * 32*512 * 4B = 262,144
#define WS_NEED 47988736ull

#define HO 19660800ull   // h_n offset in d_out (floats)
#define CO 19693568ull   // c_n offset in d_out (floats)

#define HROW 516         // padded LDS row stride (u16 elems): +4 pad -> cheap banks

__device__ __forceinline__ u16 f2bf(float f) {
  union { float f; unsigned u; } v; v.f = f;
  unsigned r = v.u + 0x7FFFu + ((v.u >> 16) & 1u);
  return (u16)(r >> 16);
}
__device__ __forceinline__ float sigm(float x) { return 1.f / (1.f + __expf(-x)); }
__device__ __forceinline__ float tanh_s(float x) {
  float ax = fabsf(x);
  float e = __expf(-2.f * ax);          // in (0,1], no overflow
  float t = (1.f - e) / (1.f + e);
  return x < 0.f ? -t : t;
}

// device-coherent 8B load / 4B store (global_load/store with sc0 sc1, LLC-direct)
__device__ __forceinline__ u64 ld_dev64(const u32* p) {
  return __hip_atomic_load((const u64*)p, __ATOMIC_RELAXED, __HIP_MEMORY_SCOPE_AGENT);
}
__device__ __forceinline__ void st_dev32(u32* p, unsigned v) {
  __hip_atomic_store(p, v, __ATOMIC_RELAXED, __HIP_MEMORY_SCOPE_AGENT);
}

// ---------------- cast x (f32 -> bf16), 4 elems/thread ----------------
__global__ __launch_bounds__(256) void cast_x_k(const float4* __restrict__ x,
                                                u16* __restrict__ xb) {
  int i = blockIdx.x * 256 + threadIdx.x;   // 4,915,200 threads
  float4 v = x[i];
  u16x4 o;
  o.x = f2bf(v.x); o.y = f2bf(v.y); o.z = f2bf(v.z); o.w = f2bf(v.w);
  *(u16x4*)(xb + (size_t)i * 4) = o;
}

// ---------------- concat + cast weights, fold biases ----------------
__global__ __launch_bounds__(256) void prep_w_k(
    const float* __restrict__ wih_f, const float* __restrict__ whh_f,
    const float* __restrict__ bih_f, const float* __restrict__ bhh_f,
    const float* __restrict__ wih_b, const float* __restrict__ whh_b,
    const float* __restrict__ bih_b, const float* __restrict__ bhh_b,
    u16* __restrict__ Wih, u16* __restrict__ Whh, float* __restrict__ bias) {
  int tid = blockIdx.x * 256 + threadIdx.x;   // 0 .. 4096*512-1
  int g = tid >> 9;
  float vi, vh;
  if (g < 2048) { vi = wih_f[tid]; vh = whh_f[tid]; }
  else { int t2 = tid - (2048 * 512); vi = wih_b[t2]; vh = whh_b[t2]; }
  Wih[tid] = f2bf(vi);
  Whh[tid] = f2bf(vh);
  if ((tid & 511) == 0) {
    bias[g] = (g < 2048) ? (bih_f[g] + bhh_f[g]) : (bih_b[g - 2048] + bhh_b[g - 2048]);
  }
}

// ---------------- persistent bidirectional LSTM recurrence ----------------
// R10: R9 worker structure UNCHANGED (waves 0-3). Added: waves 4-7 are
// DPM-filler waves on the SAME CUs (2 waves/SIMD) running calibrated FMA
// bursts between the same two barriers per step. Theory: both MfmaUtil and
// VALUBusy independently imply effective SCLK ~730 MHz (97%-stalled kernel
// -> governor parks clocks); same-CU activity should raise SCLK. Burst sizes
// (3072 cy during poll phase, 512 cy during MFMA phase) sit under each
// phase's measured duration so the critical path is not extended — worst
// case neutral, upside ~3x. LDS padded >80 KB to pin 1 block/CU.
__global__ __launch_bounds__(512, 1) void lstm_rec(const u16* __restrict__ X,
                                                   const u16* __restrict__ Wih,
                                                   const u16* __restrict__ Whh,
                                                   const float* __restrict__ bias,
                                                   const int* __restrict__ lengths,
                                                   u32* __restrict__ hbuf,
                                                   float* __restrict__ out) {
  const int tid = threadIdx.x, lane = tid & 63;
  const int bx = blockIdx.x;
  const int dir = bx >> 5, slice = bx & 31, c0 = slice * 16;
  const int quad = lane >> 4, l15 = lane & 15;

  __shared__ alignas(16) u16 h_l[32 * HROW];   // staged h(t), padded rows
  __shared__ float pre[4][32][16];
  __shared__ float s_out[8 * 512];             // 8-step out buffer (per-thread slots)
  __shared__ int len_s[32];
  __shared__ char lds_pad[28672];              // force 1 block/CU (total >84 KB)

  if (tid < 32) len_s[tid] = lengths[tid];
  ((volatile char*)lds_pad)[tid] = 0;          // keep pad allocated
  __syncthreads();   // len_s ready (single common barrier before split)

  if (tid >= 256) {
    // ================= DPM-filler waves (4-7) =================
    float f0 = 1.0f + tid, f1 = 2.0f + tid, f2 = 3.0f + tid, f3 = 4.0f + tid;
    for (int t = 0; t < T_LEN; ++t) {
      // burst A (~3072 cy): overlaps workers' poll/prefetch/unpack phase
#pragma unroll 4
      for (int i = 0; i < 384; ++i) {
        f0 = __builtin_fmaf(f0, 0.99999988f, 1e-7f);
        f1 = __builtin_fmaf(f1, 0.99999976f, 1e-7f);
        f2 = __builtin_fmaf(f2, 0.99999964f, 1e-7f);
        f3 = __builtin_fmaf(f3, 0.99999952f, 1e-7f);
      }
      __syncthreads();   // B1
      // burst B (~512 cy): overlaps workers' MFMA/LDS-read phase
#pragma unroll 4
      for (int i = 0; i < 64; ++i) {
        f0 = __builtin_fmaf(f0, 0.99999988f, 1e-7f);
        f1 = __builtin_fmaf(f1, 0.99999976f, 1e-7f);
        f2 = __builtin_fmaf(f2, 0.99999964f, 1e-7f);
        f3 = __builtin_fmaf(f3, 0.99999952f, 1e-7f);
      }
      __syncthreads();   // B2
      asm volatile("" : "+v"(f0), "+v"(f1), "+v"(f2), "+v"(f3));
    }
    if (f0 == 3.402823466e38f) out[0] = f1;    // keep chains live; never true
    return;
  }

  // ================= worker waves (0-3): R9 structure =================
  const int wid = tid >> 6;

  // B-fragments (resident whole loop): wave `wid` owns gate `wid` (i/f/g/o),
  // 16 gate cols. B[k][n] layout: n = l15, k = ks*32 + quad*8 + j.
  bf16x8 bh[16], bxw[16];
  {
    const size_t wrow = (size_t)(dir * 2048 + wid * 512 + c0 + l15) * 512 + quad * 8;
#pragma unroll
    for (int ks = 0; ks < 16; ++ks) {
      bh[ks]  = *(const bf16x8*)(Whh + wrow + (size_t)ks * 32);
      bxw[ks] = *(const bf16x8*)(Wih + wrow + (size_t)ks * 32);
    }
  }

  const int b0 = tid >> 4, colv = tid & 15, b1 = b0 + 16;
  const int hcol = c0 + colv;
  const float bi  = bias[dir * 2048 + 0 * 512 + hcol];
  const float bfv = bias[dir * 2048 + 1 * 512 + hcol];
  const float bg  = bias[dir * 2048 + 2 * 512 + hcol];
  const float bo  = bias[dir * 2048 + 3 * 512 + hcol];

  float hreg0 = 0.f, hreg1 = 0.f, creg0 = 0.f, creg1 = 0.f;
  const int len0 = len_s[b0], len1 = len_s[b1];
  const int ba = l15, bb = 16 + l15;
  const int lena = len_s[ba], lenb = len_s[bb];

  // ---- prologue: prefetch x(0) fragments into registers ----
  bf16x8 ax0[16], ax1[16];
  {
    int tta = (dir == 0) ? 0 : (lena - 1);  if (tta < 0) tta = 0;
    int ttb = (dir == 0) ? 0 : (lenb - 1);  if (ttb < 0) ttb = 0;
    const u16* xrow0 = X + ((size_t)tta * 32 + ba) * 512 + quad * 8;
    const u16* xrow1 = X + ((size_t)ttb * 32 + bb) * 512 + quad * 8;
#pragma unroll
    for (int ks = 0; ks < 16; ++ks) {
      ax0[ks] = *(const bf16x8*)(xrow0 + (size_t)ks * 32);
      ax1[ks] = *(const bf16x8*)(xrow1 + (size_t)ks * 32);
    }
  }

  for (int t = 0; t < T_LEN; ++t) {
    u32* cur = hbuf + (size_t)(((t & 1) * 2 + dir) * 16384);
    u32* nxt = hbuf + (size_t)((((t + 1) & 1) * 2 + dir) * 16384);

    // ---- issue h poll loads FIRST (the long pole) ----
    u64 stg[32];
#pragma unroll
    for (int j = 0; j < 32; ++j)
      stg[j] = ld_dev64(cur + j * 512 + tid * 2);

    // ---- x-part MFMAs: registers only (prefetched last step) — issue
    //      entirely under the poll round trip, zero vmem wait ----
    f32x4 a0x = {0.f,0.f,0.f,0.f}, a1x = {0.f,0.f,0.f,0.f};
#pragma unroll
    for (int ks = 0; ks < 16; ++ks) {
      a0x = __builtin_amdgcn_mfma_f32_16x16x32_bf16(ax0[ks], bxw[ks], a0x, 0, 0, 0);
      a1x = __builtin_amdgcn_mfma_f32_16x16x32_bf16(ax1[ks], bxw[ks], a1x, 0, 0, 0);
    }

    // ---- poll: retry until every word carries tag t ----
    const u64 e2 = ((u64)(u32)t << 32) | (u32)t;
    for (;;) {
      u64 bad = 0;
#pragma unroll
      for (int j = 0; j < 32; ++j) bad |= (stg[j] ^ e2);
      if ((bad & 0x0000FFFF0000FFFFull) == 0) break;
#pragma unroll
      for (int j = 0; j < 32; ++j)
        stg[j] = ld_dev64(cur + j * 512 + tid * 2);
    }

    // ---- prefetch x(t+1): issues now, retires under cell+publish+next poll.
    //      WAR on ax is safe: this iter's x-MFMAs already issued (in-order). ----
    {
      int tn = t + 1;
      int tta = (dir == 0) ? (tn < T_LEN ? tn : T_LEN - 1) : (lena - 1 - tn);
      int ttb = (dir == 0) ? (tn < T_LEN ? tn : T_LEN - 1) : (lenb - 1 - tn);
      if (tta < 0) tta = 0;
      if (ttb < 0) ttb = 0;
      const u16* xrow0 = X + ((size_t)tta * 32 + ba) * 512 + quad * 8;
      const u16* xrow1 = X + ((size_t)ttb * 32 + bb) * 512 + quad * 8;
#pragma unroll
      for (int ks = 0; ks < 16; ++ks) {
        ax0[ks] = *(const bf16x8*)(xrow0 + (size_t)ks * 32);
        ax1[ks] = *(const bf16x8*)(xrow1 + (size_t)ks * 32);
      }
    }

    // ---- unpack h payload into padded LDS image (row j = batch j) ----
#pragma unroll
    for (int j = 0; j < 32; ++j) {
      u32 d0 = (u32)stg[j], d1 = (u32)(stg[j] >> 32);
      *(u32*)&h_l[j * HROW + tid * 2] = (d0 >> 16) | (d1 & 0xFFFF0000u);
    }
    __syncthreads();   // B1: h image ready

    // ---- h-part MFMAs from LDS fragments (2 more independent chains) ----
    f32x4 a0h = {0.f,0.f,0.f,0.f}, a1h = {0.f,0.f,0.f,0.f};
    const u16* hl0 = h_l + (size_t)l15 * HROW + quad * 8;
    const u16* hl1 = h_l + (size_t)(16 + l15) * HROW + quad * 8;
#pragma unroll
    for (int ks = 0; ks < 16; ++ks) {
      bf16x8 f0 = *(const bf16x8*)(hl0 + ks * 32);
      bf16x8 f1 = *(const bf16x8*)(hl1 + ks * 32);
      a0h = __builtin_amdgcn_mfma_f32_16x16x32_bf16(f0, bh[ks], a0h, 0, 0, 0);
      a1h = __builtin_amdgcn_mfma_f32_16x16x32_bf16(f1, bh[ks], a1h, 0, 0, 0);
    }
    f32x4 acc0 = a0x + a0h, acc1 = a1x + a1h;
    // C/D layout: row (=batch in tile) = quad*4+r, col (=gate col) = l15
#pragma unroll
    for (int r = 0; r < 4; ++r) {
      pre[wid][quad * 4 + r][l15]      = acc0[r];
      pre[wid][16 + quad * 4 + r][l15] = acc1[r];
    }
    __syncthreads();   // B2: pre ready (also fences h_l reads vs next-iter writes)

    // ---- cell update (per-thread state in registers) ----
    float hn0 = 0.f, hn1 = 0.f;
    if (t < len0) {
      float gi = pre[0][b0][colv] + bi,  gf = pre[1][b0][colv] + bfv;
      float gg = pre[2][b0][colv] + bg,  go = pre[3][b0][colv] + bo;
      float cn = sigm(gf) * creg0 + sigm(gi) * tanh_s(gg);
      hn0 = sigm(go) * tanh_s(cn);
      creg0 = cn; hreg0 = hn0;
    }
    if (t < len1) {
      float gi = pre[0][b1][colv] + bi,  gf = pre[1][b1][colv] + bfv;
      float gg = pre[2][b1][colv] + bg,  go = pre[3][b1][colv] + bo;
      float cn = sigm(gf) * creg1 + sigm(gi) * tanh_s(gg);
      hn1 = sigm(go) * tanh_s(cn);
      creg1 = cn; hreg1 = hn1;
    }

    // ---- publish tagged h(t+1): fire-and-forget LLC stores ----
    const u32 tag = (u32)(t + 1);
    st_dev32(nxt + (size_t)b0 * 512 + hcol, ((u32)f2bf(hreg0) << 16) | tag);
    st_dev32(nxt + (size_t)b1 * 512 + hcol, ((u32)f2bf(hreg1) << 16) | tag);

    // ---- out accumulation: buffer 8 steps (private LDS slots), burst-flush.
    //      Atomic acks retire under later polls, off the critical chain. ----
    s_out[(t & 7) * 512 + tid]       = hn0;
    s_out[(t & 7) * 512 + 256 + tid] = hn1;
    if ((t & 7) == 7) {
#pragma unroll
      for (int k = 0; k < 8; ++k) {
        int ts = t - 7 + k;
        if (ts < len0) {
          int tt = (dir == 0) ? ts : (len0 - 1 - ts);
          atomicAdd(out + (size_t)(tt * 32 + b0) * 512 + hcol, s_out[k * 512 + tid]);
        }
        if (ts < len1) {
          int tt = (dir == 0) ? ts : (len1 - 1 - ts);
          atomicAdd(out + (size_t)(tt * 32 + b1) * 512 + hcol, s_out[k * 512 + 256 + tid]);
        }
      }
    }
  }

  // finals: h_n (2,B,H), c_n (2,B,H)
  out[HO + (size_t)dir * 16384 + (size_t)b0 * 512 + hcol] = hreg0;
  out[HO + (size_t)dir * 16384 + (size_t)b1 * 512 + hcol] = hreg1;
  out[CO + (size_t)dir * 16384 + (size_t)b0 * 512 + hcol] = creg0;
  out[CO + (size_t)dir * 16384 + (size_t)b1 * 512 + hcol] = creg1;
}

extern "C" void kernel_launch(void* const* d_in, const int* in_sizes, int n_in,
                              void* d_out, int out_size, void* d_ws, size_t ws_size,
                              hipStream_t stream) {
  const float* x     = (const float*)d_in[0];
  const int*   lens  = (const int*)d_in[1];
  const float* wih_f = (const float*)d_in[2];
  const float* whh_f = (const float*)d_in[3];
  const float* bih_f = (const float*)d_in[4];
  const float* bhh_f = (const float*)d_in[5];
  const float* wih_b = (const float*)d_in[6];
  const float* whh_b = (const float*)d_in[7];
  const float* bih_b = (const float*)d_in[8];
  const float* bhh_b = (const float*)d_in[9];
  float* out = (float*)d_out;
  char* ws = (char*)d_ws;

  u16*   xb   = (u16*)(ws + O_X);
  u16*   Wih  = (u16*)(ws + O_WIH);
  u16*   Whh  = (u16*)(ws + O_WHH);
  float* bias = (float*)(ws + O_BIAS);
  u32*   hbuf = (u32*)(ws + O_HBUF);

  hipMemsetAsync(hbuf, 0, 262144, stream);                 // tag 0 == h(0) == 0
  hipMemsetAsync(d_out, 0, (size_t)out_size * 4, stream);  // out accumulated via atomics

  cast_x_k<<<19200, 256, 0, stream>>>((const float4*)x, xb);
  prep_w_k<<<8192, 256, 0, stream>>>(wih_f, whh_f, bih_f, bhh_f,
                                     wih_b, whh_b, bih_b, bhh_b, Wih, Whh, bias);
  lstm_rec<<<64, 512, 0, stream>>>(xb, Wih, Whh, bias, lens, hbuf, out);
}

// Round 6
// 11067.692 us; speedup vs baseline: 1.7489x; 1.7489x over previous
//
#include <hip/hip_runtime.h>
#include <cstdint>
#include <cstddef>

typedef unsigned short u16;
typedef unsigned int u32;
typedef unsigned long long u64;
typedef short bf16x8 __attribute__((ext_vector_type(8)));
typedef float f32x4 __attribute__((ext_vector_type(4)));
typedef unsigned short u16x4 __attribute__((ext_vector_type(4)));

#define T_LEN 1200

// workspace byte offsets (all 256-aligned). Total ~48.0 MB.
#define O_X     0ull           // x bf16: 38400*512*2        = 39,321,600
#define O_WIH   39321600ull    // W_ih cat bf16: 4096*512*2  =  4,194,304
#define O_WHH   43515904ull    // W_hh cat bf16: 4096*512*2  =  4,194,304
#define O_BIAS  47710208ull    // bias cat f32: 4096*4       =     16,384
#define O_HBUF  47726592ull    // tagged h dwords: 2 par * 2 dir * 32*512 * 4B = 262,144
#define O_CTL   47988736ull    // done flag
#define WS_NEED 47989248ull

#define HO 19660800ull   // h_n offset in d_out (floats)
#define CO 19693568ull   // c_n offset in d_out (floats)

#define HROW 516         // padded LDS row stride (u16 elems): +4 pad -> cheap banks

__device__ __forceinline__ u16 f2bf(float f) {
  union { float f; unsigned u; } v; v.f = f;
  unsigned r = v.u + 0x7FFFu + ((v.u >> 16) & 1u);
  return (u16)(r >> 16);
}
__device__ __forceinline__ float sigm(float x) { return 1.f / (1.f + __expf(-x)); }
__device__ __forceinline__ float tanh_s(float x) {
  float ax = fabsf(x);
  float e = __expf(-2.f * ax);          // in (0,1], no overflow
  float t = (1.f - e) / (1.f + e);
  return x < 0.f ? -t : t;
}

// device-coherent 8B load / 4B store (global_load/store with sc0 sc1, LLC-direct)
__device__ __forceinline__ u64 ld_dev64(const u32* p) {
  return __hip_atomic_load((const u64*)p, __ATOMIC_RELAXED, __HIP_MEMORY_SCOPE_AGENT);
}
__device__ __forceinline__ void st_dev32(u32* p, unsigned v) {
  __hip_atomic_store(p, v, __ATOMIC_RELAXED, __HIP_MEMORY_SCOPE_AGENT);
}

// ---------------- cast x (f32 -> bf16), 4 elems/thread ----------------
__global__ __launch_bounds__(256) void cast_x_k(const float4* __restrict__ x,
                                                u16* __restrict__ xb) {
  int i = blockIdx.x * 256 + threadIdx.x;   // 4,915,200 threads
  float4 v = x[i];
  u16x4 o;
  o.x = f2bf(v.x); o.y = f2bf(v.y); o.z = f2bf(v.z); o.w = f2bf(v.w);
  *(u16x4*)(xb + (size_t)i * 4) = o;
}

// ---------------- concat + cast weights, fold biases ----------------
__global__ __launch_bounds__(256) void prep_w_k(
    const float* __restrict__ wih_f, const float* __restrict__ whh_f,
    const float* __restrict__ bih_f, const float* __restrict__ bhh_f,
    const float* __restrict__ wih_b, const float* __restrict__ whh_b,
    const float* __restrict__ bih_b, const float* __restrict__ bhh_b,
    u16* __restrict__ Wih, u16* __restrict__ Whh, float* __restrict__ bias) {
  int tid = blockIdx.x * 256 + threadIdx.x;   // 0 .. 4096*512-1
  int g = tid >> 9;
  float vi, vh;
  if (g < 2048) { vi = wih_f[tid]; vh = whh_f[tid]; }
  else { int t2 = tid - (2048 * 512); vi = wih_b[t2]; vh = whh_b[t2]; }
  Wih[tid] = f2bf(vi);
  Whh[tid] = f2bf(vh);
  if ((tid & 511) == 0) {
    bias[g] = (g < 2048) ? (bih_f[g] + bhh_f[g]) : (bih_b[g - 2048] + bhh_b[g - 2048]);
  }
}

// ---------------- persistent bidirectional LSTM recurrence ----------------
// R11: workers (blocks 0-63) are BYTE-IDENTICAL R9 at s_setprio(1). Blocks
// 64-511 are filler blocks: separate blocks (no shared barriers, no register
// coupling — R10's confounds removed; workers keep 256-thr launch_bounds and
// ~228 VGPR). 512 blocks over 256 CUs forces doubling, so worker CUs also
// host a filler block (VGPR 2x228<=512/SIMD, LDS 2x58KB<=160KB admit the
// pairing). Fillers run a 2-chain FMA loop (~50% SIMD duty) at prio 0 — the
// prio-1 worker wins issue arbitration, bounding contention — and poll a
// done-flag every ~2048 FMAs. Clean test of the DPM clock theory (both
// MfmaUtil and VALUBusy imply effective SCLK ~730 MHz on this 97%-stalled
// kernel).
__global__ __launch_bounds__(256, 1) void lstm_rec(const u16* __restrict__ X,
                                                   const u16* __restrict__ Wih,
                                                   const u16* __restrict__ Whh,
                                                   const float* __restrict__ bias,
                                                   const int* __restrict__ lengths,
                                                   u32* __restrict__ hbuf,
                                                   float* __restrict__ out,
                                                   int* __restrict__ ctl) {
  const int tid = threadIdx.x, lane = tid & 63, wid = tid >> 6;
  const int bx = blockIdx.x;

  if (bx >= 64) {
    // ================= filler blocks: DPM clock hold, prio 0 =================
    float f0 = 1.0f + tid, f1 = 2.0f + tid;
    for (int it = 0; it < (1 << 16); ++it) {       // hard cap ~112 ms @2.4 GHz
#pragma unroll 16
      for (int i = 0; i < 256; ++i) {              // 2048 FMAs, 2 dep chains
        f0 = __builtin_fmaf(f0, 0.99999988f, 1e-8f);
        f1 = __builtin_fmaf(f1, 0.99999976f, 1e-8f);
        f0 = __builtin_fmaf(f0, 0.99999988f, 1e-8f);
        f1 = __builtin_fmaf(f1, 0.99999976f, 1e-8f);
        f0 = __builtin_fmaf(f0, 0.99999988f, 1e-8f);
        f1 = __builtin_fmaf(f1, 0.99999976f, 1e-8f);
        f0 = __builtin_fmaf(f0, 0.99999988f, 1e-8f);
        f1 = __builtin_fmaf(f1, 0.99999976f, 1e-8f);
      }
      asm volatile("" : "+v"(f0), "+v"(f1));
      if (__hip_atomic_load(ctl, __ATOMIC_RELAXED, __HIP_MEMORY_SCOPE_AGENT))
        break;
    }
    if (f0 == 3.402823466e38f) out[0] = f1;        // unreachable sink
    return;
  }

  // ================= worker blocks (0-63): R9 structure =================
  __builtin_amdgcn_s_setprio(1);                   // beat fillers at issue

  const int dir = bx >> 5, slice = bx & 31, c0 = slice * 16;
  const int quad = lane >> 4, l15 = lane & 15;

  __shared__ alignas(16) u16 h_l[32 * HROW];   // staged h(t), padded rows
  __shared__ float pre[4][32][16];
  __shared__ float s_out[8 * 512];             // 8-step out buffer (per-thread slots)
  __shared__ int len_s[32];

  if (tid < 32) len_s[tid] = lengths[tid];

  // B-fragments (resident whole loop): wave `wid` owns gate `wid` (i/f/g/o),
  // 16 gate cols. B[k][n] layout: n = l15, k = ks*32 + quad*8 + j.
  bf16x8 bh[16], bxw[16];
  {
    const size_t wrow = (size_t)(dir * 2048 + wid * 512 + c0 + l15) * 512 + quad * 8;
#pragma unroll
    for (int ks = 0; ks < 16; ++ks) {
      bh[ks]  = *(const bf16x8*)(Whh + wrow + (size_t)ks * 32);
      bxw[ks] = *(const bf16x8*)(Wih + wrow + (size_t)ks * 32);
    }
  }
  __syncthreads();   // len_s ready

  const int b0 = tid >> 4, colv = tid & 15, b1 = b0 + 16;
  const int hcol = c0 + colv;
  const float bi  = bias[dir * 2048 + 0 * 512 + hcol];
  const float bfv = bias[dir * 2048 + 1 * 512 + hcol];
  const float bg  = bias[dir * 2048 + 2 * 512 + hcol];
  const float bo  = bias[dir * 2048 + 3 * 512 + hcol];

  float hreg0 = 0.f, hreg1 = 0.f, creg0 = 0.f, creg1 = 0.f;
  const int len0 = len_s[b0], len1 = len_s[b1];
  const int ba = l15, bb = 16 + l15;
  const int lena = len_s[ba], lenb = len_s[bb];

  // ---- prologue: prefetch x(0) fragments into registers ----
  bf16x8 ax0[16], ax1[16];
  {
    int tta = (dir == 0) ? 0 : (lena - 1);  if (tta < 0) tta = 0;
    int ttb = (dir == 0) ? 0 : (lenb - 1);  if (ttb < 0) ttb = 0;
    const u16* xrow0 = X + ((size_t)tta * 32 + ba) * 512 + quad * 8;
    const u16* xrow1 = X + ((size_t)ttb * 32 + bb) * 512 + quad * 8;
#pragma unroll
    for (int ks = 0; ks < 16; ++ks) {
      ax0[ks] = *(const bf16x8*)(xrow0 + (size_t)ks * 32);
      ax1[ks] = *(const bf16x8*)(xrow1 + (size_t)ks * 32);
    }
  }

  for (int t = 0; t < T_LEN; ++t) {
    u32* cur = hbuf + (size_t)(((t & 1) * 2 + dir) * 16384);
    u32* nxt = hbuf + (size_t)((((t + 1) & 1) * 2 + dir) * 16384);

    // ---- issue h poll loads FIRST (the long pole) ----
    u64 stg[32];
#pragma unroll
    for (int j = 0; j < 32; ++j)
      stg[j] = ld_dev64(cur + j * 512 + tid * 2);

    // ---- x-part MFMAs: registers only (prefetched last step) — issue
    //      entirely under the poll round trip, zero vmem wait ----
    f32x4 a0x = {0.f,0.f,0.f,0.f}, a1x = {0.f,0.f,0.f,0.f};
#pragma unroll
    for (int ks = 0; ks < 16; ++ks) {
      a0x = __builtin_amdgcn_mfma_f32_16x16x32_bf16(ax0[ks], bxw[ks], a0x, 0, 0, 0);
      a1x = __builtin_amdgcn_mfma_f32_16x16x32_bf16(ax1[ks], bxw[ks], a1x, 0, 0, 0);
    }

    // ---- poll: retry until every word carries tag t ----
    const u64 e2 = ((u64)(u32)t << 32) | (u32)t;
    for (;;) {
      u64 bad = 0;
#pragma unroll
      for (int j = 0; j < 32; ++j) bad |= (stg[j] ^ e2);
      if ((bad & 0x0000FFFF0000FFFFull) == 0) break;
#pragma unroll
      for (int j = 0; j < 32; ++j)
        stg[j] = ld_dev64(cur + j * 512 + tid * 2);
    }

    // ---- prefetch x(t+1): issues now, retires under cell+publish+next poll.
    //      WAR on ax is safe: this iter's x-MFMAs already issued (in-order). ----
    {
      int tn = t + 1;
      int tta = (dir == 0) ? (tn < T_LEN ? tn : T_LEN - 1) : (lena - 1 - tn);
      int ttb = (dir == 0) ? (tn < T_LEN ? tn : T_LEN - 1) : (lenb - 1 - tn);
      if (tta < 0) tta = 0;
      if (ttb < 0) ttb = 0;
      const u16* xrow0 = X + ((size_t)tta * 32 + ba) * 512 + quad * 8;
      const u16* xrow1 = X + ((size_t)ttb * 32 + bb) * 512 + quad * 8;
#pragma unroll
      for (int ks = 0; ks < 16; ++ks) {
        ax0[ks] = *(const bf16x8*)(xrow0 + (size_t)ks * 32);
        ax1[ks] = *(const bf16x8*)(xrow1 + (size_t)ks * 32);
      }
    }

    // ---- unpack h payload into padded LDS image (row j = batch j) ----
#pragma unroll
    for (int j = 0; j < 32; ++j) {
      u32 d0 = (u32)stg[j], d1 = (u32)(stg[j] >> 32);
      *(u32*)&h_l[j * HROW + tid * 2] = (d0 >> 16) | (d1 & 0xFFFF0000u);
    }
    __syncthreads();   // B1: h image ready

    // ---- h-part MFMAs from LDS fragments (2 more independent chains) ----
    f32x4 a0h = {0.f,0.f,0.f,0.f}, a1h = {0.f,0.f,0.f,0.f};
    const u16* hl0 = h_l + (size_t)l15 * HROW + quad * 8;
    const u16* hl1 = h_l + (size_t)(16 + l15) * HROW + quad * 8;
#pragma unroll
    for (int ks = 0; ks < 16; ++ks) {
      bf16x8 f0 = *(const bf16x8*)(hl0 + ks * 32);
      bf16x8 f1 = *(const bf16x8*)(hl1 + ks * 32);
      a0h = __builtin_amdgcn_mfma_f32_16x16x32_bf16(f0, bh[ks], a0h, 0, 0, 0);
      a1h = __builtin_amdgcn_mfma_f32_16x16x32_bf16(f1, bh[ks], a1h, 0, 0, 0);
    }
    f32x4 acc0 = a0x + a0h, acc1 = a1x + a1h;
    // C/D layout: row (=batch in tile) = quad*4+r, col (=gate col) = l15
#pragma unroll
    for (int r = 0; r < 4; ++r) {
      pre[wid][quad * 4 + r][l15]      = acc0[r];
      pre[wid][16 + quad * 4 + r][l15] = acc1[r];
    }
    __syncthreads();   // B2: pre ready (also fences h_l reads vs next-iter writes)

    // ---- cell update (per-thread state in registers) ----
    float hn0 = 0.f, hn1 = 0.f;
    if (t < len0) {
      float gi = pre[0][b0][colv] + bi,  gf = pre[1][b0][colv] + bfv;
      float gg = pre[2][b0][colv] + bg,  go = pre[3][b0][colv] + bo;
      float cn = sigm(gf) * creg0 + sigm(gi) * tanh_s(gg);
      hn0 = sigm(go) * tanh_s(cn);
      creg0 = cn; hreg0 = hn0;
    }
    if (t < len1) {
      float gi = pre[0][b1][colv] + bi,  gf = pre[1][b1][colv] + bfv;
      float gg = pre[2][b1][colv] + bg,  go = pre[3][b1][colv] + bo;
      float cn = sigm(gf) * creg1 + sigm(gi) * tanh_s(gg);
      hn1 = sigm(go) * tanh_s(cn);
      creg1 = cn; hreg1 = hn1;
    }

    // ---- publish tagged h(t+1): fire-and-forget LLC stores ----
    const u32 tag = (u32)(t + 1);
    st_dev32(nxt + (size_t)b0 * 512 + hcol, ((u32)f2bf(hreg0) << 16) | tag);
    st_dev32(nxt + (size_t)b1 * 512 + hcol, ((u32)f2bf(hreg1) << 16) | tag);

    // ---- out accumulation: buffer 8 steps (private LDS slots), burst-flush.
    //      Atomic acks retire under later polls, off the critical chain. ----
    s_out[(t & 7) * 512 + tid]       = hn0;
    s_out[(t & 7) * 512 + 256 + tid] = hn1;
    if ((t & 7) == 7) {
#pragma unroll
      for (int k = 0; k < 8; ++k) {
        int ts = t - 7 + k;
        if (ts < len0) {
          int tt = (dir == 0) ? ts : (len0 - 1 - ts);
          atomicAdd(out + (size_t)(tt * 32 + b0) * 512 + hcol, s_out[k * 512 + tid]);
        }
        if (ts < len1) {
          int tt = (dir == 0) ? ts : (len1 - 1 - ts);
          atomicAdd(out + (size_t)(tt * 32 + b1) * 512 + hcol, s_out[k * 512 + 256 + tid]);
        }
      }
    }
  }

  // finals: h_n (2,B,H), c_n (2,B,H)
  out[HO + (size_t)dir * 16384 + (size_t)b0 * 512 + hcol] = hreg0;
  out[HO + (size_t)dir * 16384 + (size_t)b1 * 512 + hcol] = hreg1;
  out[CO + (size_t)dir * 16384 + (size_t)b0 * 512 + hcol] = creg0;
  out[CO + (size_t)dir * 16384 + (size_t)b1 * 512 + hcol] = creg1;

  // release fillers (dirs end in lockstep; bx 0 is fine)
  if (bx == 0 && tid == 0)
    __hip_atomic_store(ctl, 1, __ATOMIC_RELAXED, __HIP_MEMORY_SCOPE_AGENT);
}

extern "C" void kernel_launch(void* const* d_in, const int* in_sizes, int n_in,
                              void* d_out, int out_size, void* d_ws, size_t ws_size,
                              hipStream_t stream) {
  const float* x     = (const float*)d_in[0];
  const int*   lens  = (const int*)d_in[1];
  const float* wih_f = (const float*)d_in[2];
  const float* whh_f = (const float*)d_in[3];
  const float* bih_f = (const float*)d_in[4];
  const float* bhh_f = (const float*)d_in[5];
  const float* wih_b = (const float*)d_in[6];
  const float* whh_b = (const float*)d_in[7];
  const float* bih_b = (const float*)d_in[8];
  const float* bhh_b = (const float*)d_in[9];
  float* out = (float*)d_out;
  char* ws = (char*)d_ws;

  u16*   xb   = (u16*)(ws + O_X);
  u16*   Wih  = (u16*)(ws + O_WIH);
  u16*   Whh  = (u16*)(ws + O_WHH);
  float* bias = (float*)(ws + O_BIAS);
  u32*   hbuf = (u32*)(ws + O_HBUF);
  int*   ctl  = (int*)(ws + O_CTL);

  hipMemsetAsync(hbuf, 0, 262144 + 512, stream);           // h tags + ctl
  hipMemsetAsync(d_out, 0, (size_t)out_size * 4, stream);  // out accumulated via atomics

  cast_x_k<<<19200, 256, 0, stream>>>((const float4*)x, xb);
  prep_w_k<<<8192, 256, 0, stream>>>(wih_f, whh_f, bih_f, bhh_f,
                                     wih_b, whh_b, bih_b, bhh_b, Wih, Whh, bias);
  lstm_rec<<<512, 256, 0, stream>>>(xb, Wih, Whh, bias, lens, hbuf, out, ctl);
}